// Round 9
// baseline (194.205 us; speedup 1.0000x reference)
//
#include <hip/hip_runtime.h>

// NCC loss. Round 9: register row-ring, 2-row ticks, 1 barrier / 2 rows.
// Model R2-R8: per-CU vmem path ~9-10 B/cyc regardless of cache hits; floor
// for load-once (~100 MB unique lines) ~16.5 us. R8 hit the traffic target
// but was barrier/latency-bound (25 ticks, 1-deep prefetch, 45 KB LDS).
//  - Thread owns 2 cols; loads own float2 of I and J per row (coalesced).
//  - 7-generation register ring (rows live load->add(+2 ticks)->sub(+6)).
//    Constant indices after full unroll; masking deferred to add/sub so the
//    loads have no early consumer (prefetch depth 2 ticks survives; barriers
//    don't drain register-destined vmcnt).
//  - Horizontal 9-sum: 6 shuffles/quantity (+-2 lanes); cross-wave seams via
//    5.8 KB parity-double-buffered LDS edge patch; image edges = zero pads.
//  - 14 ticks: t=0..11 load rows 2t,2t+1; t>=2 add pair 2t-4,2t-3; t>=6
//    output rows 2t-12,2t-11 (snapshot A, sub, add B, snapshot B, sub,
//    publish both, ONE barrier, horizontal+cc both). 8 barriers total.

#define W 512
#define H 512
#define BH 16
#define NBANDS (H / BH)   // 32
#define NT 256

__global__ __launch_bounds__(NT)
void ncc_main(const float* __restrict__ I, const float* __restrict__ J,
              float* __restrict__ partials) {
    // edge patch: [parity][rowAB][slot 0..5 (0,5=zero pads)][cls][q][S,v0,v1]
    __shared__ float eb[2][2][6][4][5][3];   // 5760 B
    __shared__ float wsum[4];

    const int tid  = threadIdx.x;
    const int lane = tid & 63;
    const int wid  = tid >> 6;

    // XCD swizzle: contiguous band ranges per XCD (vertical halo L2 reuse).
    const int nblk = gridDim.x;              // 1024, divisible by 8
    const int g    = (blockIdx.x & 7) * (nblk >> 3) + (blockIdx.x >> 3);

    const int b    = g >> 5;                 // / NBANDS
    const int band = g & (NBANDS - 1);
    const int y0   = band * BH;
    const float* Ip = I + (size_t)b * (H * W);
    const float* Jp = J + (size_t)b * (H * W);
    const int c0 = tid * 2;                  // own cols c0, c0+1

    // zero whole edge patch once; barrier orders it before first publish
    for (int i = tid; i < 2 * 2 * 6 * 4 * 5 * 3; i += NT)
        (&eb[0][0][0][0][0][0])[i] = 0.f;
    __syncthreads();

    float rg[7][8];                          // [gen][iAx,iAy,jAx,jAy,iBx,iBy,jBx,jBy]
    float v[5][2];
    #pragma unroll
    for (int q = 0; q < 5; ++q) { v[q][0] = 0.f; v[q][1] = 0.f; }

    float cc_acc = 0.f;
    const float inv81 = 1.f / 81.f;

    float a0[5], a1[5], b0[5], b1[5];        // snapshots (v0,v1 per q) rows A,B

    #pragma unroll
    for (int t = 0; t < 14; ++t) {
        // ---- issue loads for rows 2t, 2t+1 into gen t%7 (raw, unmasked) ----
        if (t <= 11) {
            const int gg = t % 7;
            int r0 = y0 - 4 + 2 * t;
            int rc0 = r0 < 0 ? 0 : (r0 > H - 1 ? H - 1 : r0);
            int r1 = r0 + 1;
            int rc1 = r1 < 0 ? 0 : (r1 > H - 1 ? H - 1 : r1);
            float2 iA = *(const float2*)(Ip + rc0 * W + c0);
            float2 jA = *(const float2*)(Jp + rc0 * W + c0);
            float2 iB = *(const float2*)(Ip + rc1 * W + c0);
            float2 jB = *(const float2*)(Jp + rc1 * W + c0);
            rg[gg][0] = iA.x; rg[gg][1] = iA.y; rg[gg][2] = jA.x; rg[gg][3] = jA.y;
            rg[gg][4] = iB.x; rg[gg][5] = iB.y; rg[gg][6] = jB.x; rg[gg][7] = jB.y;
        }

        // masks recomputed from row index (wave-uniform scalar, no vmcnt use)
        #define MSK(k) ((y0 - 4 + (k)) >= 0 && (y0 - 4 + (k)) < H ? 1.f : 0.f)

        #define VOP(gg, off, m, OP) do {                                      \
            float _i0 = rg[gg][(off)+0], _i1 = rg[gg][(off)+1];               \
            float _j0 = rg[gg][(off)+2], _j1 = rg[gg][(off)+3];               \
            float _mi0 = (m) * _i0, _mi1 = (m) * _i1;                         \
            float _mj0 = (m) * _j0, _mj1 = (m) * _j1;                         \
            v[0][0] OP _mi0;        v[0][1] OP _mi1;                          \
            v[1][0] OP _mj0;        v[1][1] OP _mj1;                          \
            v[2][0] OP _mi0 * _i0;  v[2][1] OP _mi1 * _i1;                    \
            v[3][0] OP _mj0 * _j0;  v[3][1] OP _mj1 * _j1;                    \
            v[4][0] OP _mi0 * _j0;  v[4][1] OP _mi1 * _j1;                    \
        } while (0)

        // ---- add row A = 2t-4 (gen t-2) ----
        if (t >= 2) { float m = MSK(2 * t - 4); VOP((t - 2) % 7, 0, m, +=); }
        // ---- output row A = 2t-12: snapshot, then sub (gen t-6, row A) ----
        if (t >= 6) {
            #pragma unroll
            for (int q = 0; q < 5; ++q) { a0[q] = v[q][0]; a1[q] = v[q][1]; }
            float m = MSK(2 * t - 12); VOP((t - 6) % 7, 0, m, -=);
        }
        // ---- add row B = 2t-3 (gen t-2) ----
        if (t >= 2) { float m = MSK(2 * t - 3); VOP((t - 2) % 7, 4, m, +=); }
        // ---- output row B = 2t-11: snapshot, then sub (gen t-6, row B) ----
        if (t >= 6) {
            #pragma unroll
            for (int q = 0; q < 5; ++q) { b0[q] = v[q][0]; b1[q] = v[q][1]; }
            float m = MSK(2 * t - 11); VOP((t - 6) % 7, 4, m, -=);

            const int par = t & 1;
            const int cls = lane == 0 ? 0 : lane == 1 ? 1 :
                            lane == 62 ? 2 : lane == 63 ? 3 : -1;
            if (cls >= 0) {
                #pragma unroll
                for (int q = 0; q < 5; ++q) {
                    eb[par][0][wid + 1][cls][q][0] = a0[q] + a1[q];
                    eb[par][0][wid + 1][cls][q][1] = a0[q];
                    eb[par][0][wid + 1][cls][q][2] = a1[q];
                    eb[par][1][wid + 1][cls][q][0] = b0[q] + b1[q];
                    eb[par][1][wid + 1][cls][q][1] = b0[q];
                    eb[par][1][wid + 1][cls][q][2] = b1[q];
                }
            }
            __syncthreads();

            #define HROW(x0a, x1a, ab) do {                                   \
                float h0[5], h1[5];                                           \
                _Pragma("unroll")                                             \
                for (int q = 0; q < 5; ++q) {                                 \
                    float S    = x0a[q] + x1a[q];                             \
                    float Sm2  = __shfl_up(S, 2);                             \
                    float Sm1  = __shfl_up(S, 1);                             \
                    float v0m2 = __shfl_up(x0a[q], 2);                        \
                    float Sp1  = __shfl_down(S, 1);                           \
                    float v0p2 = __shfl_down(x0a[q], 2);                      \
                    float v1p2 = __shfl_down(x1a[q], 2);                      \
                    if (lane == 0) {                                          \
                        Sm2  = eb[par][ab][wid][2][q][0];                     \
                        Sm1  = eb[par][ab][wid][3][q][0];                     \
                        v0m2 = eb[par][ab][wid][2][q][1];                     \
                    } else if (lane == 1) {                                   \
                        Sm2  = eb[par][ab][wid][3][q][0];                     \
                        v0m2 = eb[par][ab][wid][3][q][1];                     \
                    }                                                         \
                    if (lane == 63) {                                         \
                        Sp1  = eb[par][ab][wid + 2][0][q][0];                 \
                        v0p2 = eb[par][ab][wid + 2][1][q][1];                 \
                        v1p2 = eb[par][ab][wid + 2][1][q][2];                 \
                    } else if (lane == 62) {                                  \
                        v0p2 = eb[par][ab][wid + 2][0][q][1];                 \
                        v1p2 = eb[par][ab][wid + 2][0][q][2];                 \
                    }                                                         \
                    float t9 = ((Sm2 + Sm1) + (S + Sp1)) + v0p2;              \
                    h0[q] = t9;                                               \
                    h1[q] = (t9 - v0m2) + v1p2;                               \
                }                                                             \
                {                                                             \
                    float Is = h0[0], Js = h0[1];                             \
                    float u  = Is * inv81;                                    \
                    float cr = h0[4] - u * Js;                                \
                    float Iv = h0[2] - u * Is;                                \
                    float Jv = h0[3] - (Js * inv81) * Js;                     \
                    cc_acc += cr * cr * __builtin_amdgcn_rcpf(Iv * Jv + 1e-6f); \
                }                                                             \
                {                                                             \
                    float Is = h1[0], Js = h1[1];                             \
                    float u  = Is * inv81;                                    \
                    float cr = h1[4] - u * Js;                                \
                    float Iv = h1[2] - u * Is;                                \
                    float Jv = h1[3] - (Js * inv81) * Js;                     \
                    cc_acc += cr * cr * __builtin_amdgcn_rcpf(Iv * Jv + 1e-6f); \
                }                                                             \
            } while (0)

            HROW(a0, a1, 0);
            HROW(b0, b1, 1);
        }
    }

    // reduce: wave shuffle, then 4-wave combine
    #pragma unroll
    for (int off = 32; off > 0; off >>= 1)
        cc_acc += __shfl_down(cc_acc, off, 64);
    if (lane == 0) wsum[wid] = cc_acc;
    __syncthreads();
    if (tid == 0)
        partials[blockIdx.x] = (wsum[0] + wsum[1]) + (wsum[2] + wsum[3]);
}

__global__ __launch_bounds__(256)
void ncc_finish(const float* __restrict__ partials, float* __restrict__ out,
                int n, float inv_total) {
    float v = 0.f;
    for (int i = threadIdx.x; i < n; i += blockDim.x) v += partials[i];
    #pragma unroll
    for (int off = 32; off > 0; off >>= 1)
        v += __shfl_down(v, off, 64);
    __shared__ float wsum[4];
    if ((threadIdx.x & 63) == 0) wsum[threadIdx.x >> 6] = v;
    __syncthreads();
    if (threadIdx.x == 0) {
        float t = (wsum[0] + wsum[1]) + (wsum[2] + wsum[3]);
        out[0] = 1.0f - t * inv_total;
    }
}

extern "C" void kernel_launch(void* const* d_in, const int* in_sizes, int n_in,
                              void* d_out, int out_size, void* d_ws, size_t ws_size,
                              hipStream_t stream) {
    const float* I = (const float*)d_in[0];   // predict
    const float* J = (const float*)d_in[1];   // target
    float* out = (float*)d_out;
    float* partials = (float*)d_ws;           // nblocks floats

    const int n = in_sizes[0];                // B*1*H*W
    const int B = n / (H * W);
    const int nblocks = B * NBANDS;           // 1024 for B=32

    ncc_main<<<nblocks, NT, 0, stream>>>(I, J, partials);
    ncc_finish<<<1, 256, 0, stream>>>(partials, out, nblocks, 1.0f / (float)n);
}

// Round 10
// 108.246 us; speedup vs baseline: 1.7941x; 1.7941x over previous
//
#include <hip/hip_runtime.h>

// NCC loss. Round 10: wave-autonomous + thread-PRIVATE LDS row ring.
// Model (R2-R9): dur = L1-miss bytes / ~6.1 TB/s given (a) no barriers in the
// loop (__syncthreads drains vmcnt -> kills prefetch, R8), (b) rolled loop
// (I-cache, R7), (c) no register-array rings (spill, R4/R9), (d) explicit
// named ping-pong prefetch. Load-once: 24 rows/band of 16 outputs = 100 MB
// total -> 16.4 us floor.
//  - 1 wave = 1 band (BH=16) x 512 cols, 8 cols/lane; horizontal 9-sum via
//    +-1-lane shuffles (R6-proven HLO/HHI).
//  - Raw masked rows parked in an 8-slot LDS ring, PRIVATE per lane (lane
//    subs exactly what it added) -> zero synchronization. Layout
//    [slot][chunk][lane][4] = 16B lane stride, conflict-free ds_b128.
//  - Depth-2 global prefetch via named P/Q buffers; sub-row ds_read issued
//    at tick top, consumed at tick end.
//  - 1024 single-wave blocks; 4 blocks/CU (32 KB LDS each).

#define W 512
#define H 512
#define BH 16
#define NBANDS (H / BH)   // 32
#define NT 64

__device__ __forceinline__ float4 ld4(const float* p) {
    return *reinterpret_cast<const float4*>(p);
}

#define DECLP(P) float4 P##A0, P##A1, P##B0, P##B1; float P##m

// Load row ROW (clamped); mask 1 if in range else 0. Data unused here.
#define LOADP(P, ROW) do {                                                   \
    int _r  = (ROW);                                                         \
    int _rc = _r < 0 ? 0 : (_r > H - 1 ? H - 1 : _r);                        \
    const float* _ip = Ip + _rc * W + x0;                                    \
    const float* _jp = Jp + _rc * W + x0;                                    \
    P##A0 = ld4(_ip);  P##A1 = ld4(_ip + 4);                                 \
    P##B0 = ld4(_jp);  P##B1 = ld4(_jp + 4);                                 \
    P##m  = (_r == _rc) ? 1.f : 0.f;                                         \
} while (0)

// Masked add into v* AND park masked raw row in ring slot BASE (float*).
// m in {0,1}: (m*a)*(m*a) = m*a*a, (m*a)*(m*b) = m*a*b -> all products from
// masked values; sub later needs no mask.
#define MADDW(P, BASE) do {                                                  \
    float _m = P##m;                                                         \
    float _f0=P##A0.x*_m, _f1=P##A0.y*_m, _f2=P##A0.z*_m, _f3=P##A0.w*_m;    \
    float _f4=P##A1.x*_m, _f5=P##A1.y*_m, _f6=P##A1.z*_m, _f7=P##A1.w*_m;    \
    float _g0=P##B0.x*_m, _g1=P##B0.y*_m, _g2=P##B0.z*_m, _g3=P##B0.w*_m;    \
    float _g4=P##B1.x*_m, _g5=P##B1.y*_m, _g6=P##B1.z*_m, _g7=P##B1.w*_m;    \
    v0[0]+=_f0; v0[1]+=_f1; v0[2]+=_f2; v0[3]+=_f3;                          \
    v0[4]+=_f4; v0[5]+=_f5; v0[6]+=_f6; v0[7]+=_f7;                          \
    v1[0]+=_g0; v1[1]+=_g1; v1[2]+=_g2; v1[3]+=_g3;                          \
    v1[4]+=_g4; v1[5]+=_g5; v1[6]+=_g6; v1[7]+=_g7;                          \
    v2[0]+=_f0*_f0; v2[1]+=_f1*_f1; v2[2]+=_f2*_f2; v2[3]+=_f3*_f3;          \
    v2[4]+=_f4*_f4; v2[5]+=_f5*_f5; v2[6]+=_f6*_f6; v2[7]+=_f7*_f7;          \
    v3[0]+=_g0*_g0; v3[1]+=_g1*_g1; v3[2]+=_g2*_g2; v3[3]+=_g3*_g3;          \
    v3[4]+=_g4*_g4; v3[5]+=_g5*_g5; v3[6]+=_g6*_g6; v3[7]+=_g7*_g7;          \
    v4[0]+=_f0*_g0; v4[1]+=_f1*_g1; v4[2]+=_f2*_g2; v4[3]+=_f3*_g3;          \
    v4[4]+=_f4*_g4; v4[5]+=_f5*_g5; v4[6]+=_f6*_g6; v4[7]+=_f7*_g7;          \
    *(float4*)((BASE)      ) = make_float4(_f0,_f1,_f2,_f3);                 \
    *(float4*)((BASE) + 256) = make_float4(_f4,_f5,_f6,_f7);                 \
    *(float4*)((BASE) + 512) = make_float4(_g0,_g1,_g2,_g3);                 \
    *(float4*)((BASE) + 768) = make_float4(_g4,_g5,_g6,_g7);                 \
} while (0)

#define RSUB_READ(BASE) do {                                                 \
    rs0 = *(const float4*)((BASE)      );                                    \
    rs1 = *(const float4*)((BASE) + 256);                                    \
    rs2 = *(const float4*)((BASE) + 512);                                    \
    rs3 = *(const float4*)((BASE) + 768);                                    \
} while (0)

#define VSUBR() do {                                                         \
    v0[0]-=rs0.x; v0[1]-=rs0.y; v0[2]-=rs0.z; v0[3]-=rs0.w;                  \
    v0[4]-=rs1.x; v0[5]-=rs1.y; v0[6]-=rs1.z; v0[7]-=rs1.w;                  \
    v1[0]-=rs2.x; v1[1]-=rs2.y; v1[2]-=rs2.z; v1[3]-=rs2.w;                  \
    v1[4]-=rs3.x; v1[5]-=rs3.y; v1[6]-=rs3.z; v1[7]-=rs3.w;                  \
    v2[0]-=rs0.x*rs0.x; v2[1]-=rs0.y*rs0.y; v2[2]-=rs0.z*rs0.z; v2[3]-=rs0.w*rs0.w; \
    v2[4]-=rs1.x*rs1.x; v2[5]-=rs1.y*rs1.y; v2[6]-=rs1.z*rs1.z; v2[7]-=rs1.w*rs1.w; \
    v3[0]-=rs2.x*rs2.x; v3[1]-=rs2.y*rs2.y; v3[2]-=rs2.z*rs2.z; v3[3]-=rs2.w*rs2.w; \
    v3[4]-=rs3.x*rs3.x; v3[5]-=rs3.y*rs3.y; v3[6]-=rs3.z*rs3.z; v3[7]-=rs3.w*rs3.w; \
    v4[0]-=rs0.x*rs2.x; v4[1]-=rs0.y*rs2.y; v4[2]-=rs0.z*rs2.z; v4[3]-=rs0.w*rs2.w; \
    v4[4]-=rs1.x*rs3.x; v4[5]-=rs1.y*rs3.y; v4[6]-=rs1.z*rs3.z; v4[7]-=rs1.w*rs3.w; \
} while (0)

// Horizontal 9-sum, lo half (cols 0..3 of this lane); exports l7 for hi.
#define HLO(vv, h, l7out) do {                                               \
    float _l4 = __shfl_up(vv[4], 1), _l5 = __shfl_up(vv[5], 1);              \
    float _l6 = __shfl_up(vv[6], 1), _l7 = __shfl_up(vv[7], 1);              \
    if (lane == 0) { _l4 = 0.f; _l5 = 0.f; _l6 = 0.f; _l7 = 0.f; }           \
    float _t = (((_l4+_l5)+(_l6+_l7)) + ((vv[0]+vv[1])+(vv[2]+vv[3]))) + vv[4]; \
    h[0] = _t;                                                               \
    _t += vv[5] - _l4; h[1] = _t;                                            \
    _t += vv[6] - _l5; h[2] = _t;                                            \
    _t += vv[7] - _l6; h[3] = _t;                                            \
    l7out = _l7;                                                             \
} while (0)

// Horizontal 9-sum, hi half (cols 4..7), chained from h3/l7.
#define HHI(vv, h3in, l7in, h) do {                                          \
    float _r0 = __shfl_down(vv[0], 1), _r1 = __shfl_down(vv[1], 1);          \
    float _r2 = __shfl_down(vv[2], 1), _r3 = __shfl_down(vv[3], 1);          \
    if (lane == 63) { _r0 = 0.f; _r1 = 0.f; _r2 = 0.f; _r3 = 0.f; }          \
    float _t = (h3in) + _r0 - (l7in); h[0] = _t;                             \
    _t += _r1 - vv[0]; h[1] = _t;                                            \
    _t += _r2 - vv[1]; h[2] = _t;                                            \
    _t += _r3 - vv[2]; h[3] = _t;                                            \
} while (0)

#define CC4(h0a, h1a, h2a, h3a, h4a) do {                                    \
    _Pragma("unroll")                                                        \
    for (int _c = 0; _c < 4; ++_c) {                                         \
        float _Is = h0a[_c], _Js = h1a[_c];                                  \
        float _u  = _Is * inv81;                                             \
        float _cr = h4a[_c] - _u * _Js;                                      \
        float _Iv = h2a[_c] - _u * _Is;                                      \
        float _Jv = h3a[_c] - (_Js * inv81) * _Js;                           \
        cc_acc += (_cr * _cr) * __builtin_amdgcn_rcpf(_Iv * _Jv + 1e-6f);    \
    }                                                                        \
} while (0)

#define EPI() do {                                                           \
    float h0[4], h1[4], h2[4], h3[4], h4[4];                                 \
    float s0, s1, s2, s3, s4;                                                \
    HLO(v0, h0, s0); HLO(v1, h1, s1); HLO(v2, h2, s2);                       \
    HLO(v3, h3, s3); HLO(v4, h4, s4);                                        \
    CC4(h0, h1, h2, h3, h4);                                                 \
    float e0 = h0[3], e1 = h1[3], e2 = h2[3], e3 = h3[3], e4 = h4[3];        \
    HHI(v0, e0, s0, h0); HHI(v1, e1, s1, h1); HHI(v2, e2, s2, h2);           \
    HHI(v3, e3, s3, h3); HHI(v4, e4, s4, h4);                                \
    CC4(h0, h1, h2, h3, h4);                                                 \
} while (0)

__global__ __launch_bounds__(NT)
void ncc_main(const float* __restrict__ I, const float* __restrict__ J,
              float* __restrict__ partials) {
    // ring[slot][chunk][lane][4]: chunk 0/1 = I cols 0-3/4-7, 2/3 = J.
    __shared__ float ring[8][4][NT][4];   // 32 KB, lane-private slots

    const int lane = threadIdx.x;         // single-wave block

    // XCD swizzle: contiguous band ranges per XCD (halo rows share L2).
    const int nblk = gridDim.x;           // 1024, divisible by 8
    const int g = (blockIdx.x & 7) * (nblk >> 3) + (blockIdx.x >> 3);

    const int b    = g >> 5;              // / NBANDS
    const int band = g & (NBANDS - 1);
    const int y0   = band * BH;
    const float* Ip = I + (size_t)b * (H * W);
    const float* Jp = J + (size_t)b * (H * W);
    const int x0 = lane * 8;

    float v0[8], v1[8], v2[8], v3[8], v4[8];
    #pragma unroll
    for (int k = 0; k < 8; ++k) { v0[k]=0.f; v1[k]=0.f; v2[k]=0.f; v3[k]=0.f; v4[k]=0.f; }

    float cc_acc = 0.f;
    const float inv81 = 1.f / 81.f;

    float* const myring = &ring[0][0][lane][0];  // slot stride = 1024 floats

    DECLP(P); DECLP(Q);

    // Prime rows y0-4..y0+3 into slots 0..7, depth-2 pipelined.
    LOADP(P, y0 - 4); LOADP(Q, y0 - 3);
    MADDW(P, myring + 0 * 1024); LOADP(P, y0 - 2);
    MADDW(Q, myring + 1 * 1024); LOADP(Q, y0 - 1);
    MADDW(P, myring + 2 * 1024); LOADP(P, y0 + 0);
    MADDW(Q, myring + 3 * 1024); LOADP(Q, y0 + 1);
    MADDW(P, myring + 4 * 1024); LOADP(P, y0 + 2);
    MADDW(Q, myring + 5 * 1024); LOADP(Q, y0 + 3);
    MADDW(P, myring + 6 * 1024);
    MADDW(Q, myring + 7 * 1024);

    // Preload fresh rows y0+4, y0+5.
    LOADP(P, y0 + 4); LOADP(Q, y0 + 5);

    float4 rs0, rs1, rs2, rs3;
    // Tick i (output row y0+i): sub-read slot i&7 (row y0+i-4, parked
    // earlier by THIS lane), add fresh row y0+4+i (also parked into the same
    // slot - DS same-address ops are in-order per wave, read precedes write),
    // issue load for row y0+6+i, horizontal+cc, then subtract.
    #pragma unroll 2
    for (int i = 0; i < 16; ++i) {
        float* sb = myring + (i & 7) * 1024;
        RSUB_READ(sb);
        if ((i & 1) == 0) {
            MADDW(P, sb);
            if (i < 14) LOADP(P, y0 + 6 + i);
        } else {
            MADDW(Q, sb);
            if (i < 14) LOADP(Q, y0 + 6 + i);
        }
        EPI();
        VSUBR();
    }

    // Single-wave reduce; lane 0 writes the block partial.
    #pragma unroll
    for (int off = 32; off > 0; off >>= 1)
        cc_acc += __shfl_down(cc_acc, off, 64);
    if (lane == 0) partials[blockIdx.x] = cc_acc;
}

__global__ __launch_bounds__(256)
void ncc_finish(const float* __restrict__ partials, float* __restrict__ out,
                int n, float inv_total) {
    float v = 0.f;
    for (int i = threadIdx.x; i < n; i += blockDim.x) v += partials[i];
    #pragma unroll
    for (int off = 32; off > 0; off >>= 1)
        v += __shfl_down(v, off, 64);
    __shared__ float wsum[4];
    if ((threadIdx.x & 63) == 0) wsum[threadIdx.x >> 6] = v;
    __syncthreads();
    if (threadIdx.x == 0) {
        float t = (wsum[0] + wsum[1]) + (wsum[2] + wsum[3]);
        out[0] = 1.0f - t * inv_total;
    }
}

extern "C" void kernel_launch(void* const* d_in, const int* in_sizes, int n_in,
                              void* d_out, int out_size, void* d_ws, size_t ws_size,
                              hipStream_t stream) {
    const float* I = (const float*)d_in[0];   // predict
    const float* J = (const float*)d_in[1];   // target
    float* out = (float*)d_out;
    float* partials = (float*)d_ws;           // nblocks floats

    const int n = in_sizes[0];                // B*1*H*W
    const int B = n / (H * W);
    const int nblocks = B * NBANDS;           // 1024 for B=32

    ncc_main<<<nblocks, NT, 0, stream>>>(I, J, partials);
    ncc_finish<<<1, 256, 0, stream>>>(partials, out, nblocks, 1.0f / (float)n);
}